// Round 1
// baseline (478.281 us; speedup 1.0000x reference)
//
#include <hip/hip_runtime.h>
#include <stdint.h>

// ---------------------------------------------------------------------------
// QuantLinear: per-row symmetric int8 W quant, per-token asymmetric int8 X
// quant, integer GEMM via mfma_i32_16x16x64_i8, fused dequant epilogue.
//
// Y[n,m] = cs[n]*rs[m]*( Sint[n,m] - zp[n]*Wsum[m] ) + b[m]
// ---------------------------------------------------------------------------

typedef __attribute__((ext_vector_type(4))) int int4v;

__device__ __forceinline__ void async_load16(const void* g, void* l) {
    // global -> LDS direct copy, 16B per lane; LDS dest is wave-uniform base
    // + lane*16 (m104/m108 semantics). l must be wave-uniform.
    __builtin_amdgcn_global_load_lds(
        (const __attribute__((address_space(1))) void*)g,
        (__attribute__((address_space(3))) void*)l, 16, 0, 0);
}

__device__ __forceinline__ int quant_clip(float v) {
    // matches np: clip(rint(v), -128, 127); rintf = round-half-even
    return (int)fminf(fmaxf(rintf(v), -128.f), 127.f);
}

// ---------------------------------------------------------------------------
// Kernel 1: weight quant. One block per row of W (K=4096 floats).
// Produces Wq (int8), row_scale, wsum (sum of Wq over the row).
// ---------------------------------------------------------------------------
__global__ __launch_bounds__(256) void wquant_kernel(
    const float* __restrict__ W, int8_t* __restrict__ Wq,
    float* __restrict__ row_scale, int* __restrict__ wsum, int K) {
    const int row  = blockIdx.x;
    const int tid  = threadIdx.x;
    const int lane = tid & 63;
    const int wv   = tid >> 6;

    const float4* w4 = (const float4*)(W + (size_t)row * K);
    float4 vals[4];
    float amax = 0.f;
#pragma unroll
    for (int i = 0; i < 4; ++i) {
        float4 v = w4[tid + i * 256];
        vals[i] = v;
        amax = fmaxf(amax, fmaxf(fmaxf(fabsf(v.x), fabsf(v.y)),
                                 fmaxf(fabsf(v.z), fabsf(v.w))));
    }
#pragma unroll
    for (int off = 32; off > 0; off >>= 1)
        amax = fmaxf(amax, __shfl_down(amax, off, 64));

    __shared__ float smax[4];
    __shared__ int   isum[4];
    if (lane == 0) smax[wv] = amax;
    __syncthreads();
    amax = fmaxf(fmaxf(smax[0], smax[1]), fmaxf(smax[2], smax[3]));

    const float scale = (amax > 0.f) ? (amax / 127.f) : 1.f;

    int ssum = 0;
    int* wq32 = (int*)(Wq + (size_t)row * K);
#pragma unroll
    for (int i = 0; i < 4; ++i) {
        float4 v = vals[i];
        int q0 = quant_clip(v.x / scale);
        int q1 = quant_clip(v.y / scale);
        int q2 = quant_clip(v.z / scale);
        int q3 = quant_clip(v.w / scale);
        ssum += q0 + q1 + q2 + q3;
        wq32[tid + i * 256] =
            (q0 & 0xff) | ((q1 & 0xff) << 8) | ((q2 & 0xff) << 16) | ((q3 & 0xff) << 24);
    }
#pragma unroll
    for (int off = 32; off > 0; off >>= 1)
        ssum += __shfl_down(ssum, off, 64);
    if (lane == 0) isum[wv] = ssum;
    __syncthreads();
    if (tid == 0) {
        wsum[row] = isum[0] + isum[1] + isum[2] + isum[3];
        row_scale[row] = scale;
    }
}

// ---------------------------------------------------------------------------
// Kernel 2: activation quant. One block per token row (K=4096 floats).
// Produces Xq (int8), col_scale, zp (integer zero-point).
// ---------------------------------------------------------------------------
__global__ __launch_bounds__(256) void xquant_kernel(
    const float* __restrict__ X, int8_t* __restrict__ Xq,
    float* __restrict__ col_scale, int* __restrict__ zp, int K) {
    const int row  = blockIdx.x;
    const int tid  = threadIdx.x;
    const int lane = tid & 63;
    const int wv   = tid >> 6;

    const float4* x4 = (const float4*)(X + (size_t)row * K);
    float4 vals[4];
    float vmin = 3.402823466e+38f, vmax = -3.402823466e+38f;
#pragma unroll
    for (int i = 0; i < 4; ++i) {
        float4 v = x4[tid + i * 256];
        vals[i] = v;
        vmin = fminf(vmin, fminf(fminf(v.x, v.y), fminf(v.z, v.w)));
        vmax = fmaxf(vmax, fmaxf(fmaxf(v.x, v.y), fmaxf(v.z, v.w)));
    }
#pragma unroll
    for (int off = 32; off > 0; off >>= 1) {
        vmin = fminf(vmin, __shfl_down(vmin, off, 64));
        vmax = fmaxf(vmax, __shfl_down(vmax, off, 64));
    }
    __shared__ float smin[4], smax[4];
    if (lane == 0) { smin[wv] = vmin; smax[wv] = vmax; }
    __syncthreads();
    vmin = fminf(fminf(smin[0], smin[1]), fminf(smin[2], smin[3]));
    vmax = fmaxf(fmaxf(smax[0], smax[1]), fmaxf(smax[2], smax[3]));

    const float rng   = vmax - vmin;
    const float scale = (rng > 0.f) ? (rng / 255.f) : 1.f;
    const float zpf   = fminf(fmaxf(rintf(-128.f - vmin / scale), -128.f), 127.f);

    int* xq32 = (int*)(Xq + (size_t)row * K);
#pragma unroll
    for (int i = 0; i < 4; ++i) {
        float4 v = vals[i];
        int q0 = quant_clip(v.x / scale + zpf);
        int q1 = quant_clip(v.y / scale + zpf);
        int q2 = quant_clip(v.z / scale + zpf);
        int q3 = quant_clip(v.w / scale + zpf);
        xq32[tid + i * 256] =
            (q0 & 0xff) | ((q1 & 0xff) << 8) | ((q2 & 0xff) << 16) | ((q3 & 0xff) << 24);
    }
    if (tid == 0) {
        col_scale[row] = scale;
        zp[row] = (int)zpf;
    }
}

// ---------------------------------------------------------------------------
// Kernel 3: int8 GEMM, m97-style structure.
//   Block tile: 128 (N) x 128 (M), BK = 64 bytes of int8.
//   256 threads = 4 waves in 2x2; each wave computes 64x64 via 4x4
//   mfma_i32_16x16x64_i8. LDS staged with global_load_lds width=16.
// ---------------------------------------------------------------------------
#define TBK 64

__global__ __launch_bounds__(256) void gemm_i8_kernel(
    const int8_t* __restrict__ Xq, const int8_t* __restrict__ Wq,
    const float* __restrict__ cs, const int* __restrict__ zp,
    const float* __restrict__ rs, const int* __restrict__ wsum,
    const float* __restrict__ bias, float* __restrict__ out,
    int N, int M, int K) {
    __shared__ __align__(16) int8_t As[128 * TBK];  // 8 KB
    __shared__ __align__(16) int8_t Bs[128 * TBK];  // 8 KB

    const int t    = threadIdx.x;
    const int wv   = t >> 6;
    const int lane = t & 63;
    const int r    = lane & 15;
    const int qd   = lane >> 4;

    const int m0 = blockIdx.x * 128;
    const int n0 = blockIdx.y * 128;
    const int wn = (wv >> 1) * 64;  // wave's N offset in tile
    const int wm = (wv & 1) * 64;   // wave's M offset in tile

    int4v acc[4][4];
#pragma unroll
    for (int i = 0; i < 4; ++i)
#pragma unroll
        for (int j = 0; j < 4; ++j)
            acc[i][j] = (int4v)(0);

    // Staging: tile is 128 rows x 64 B = 512 chunks of 16B; 256 threads -> 2.
    // Chunk c = it*256 + t lands at LDS offset c*16 (= row-major [128][64]).
    const int c0 = t, c1 = 256 + t;
    const size_t gA0 = (size_t)(n0 + (c0 >> 2)) * K + (c0 & 3) * 16;
    const size_t gA1 = (size_t)(n0 + (c1 >> 2)) * K + (c1 & 3) * 16;
    const size_t gB0 = (size_t)(m0 + (c0 >> 2)) * K + (c0 & 3) * 16;
    const size_t gB1 = (size_t)(m0 + (c1 >> 2)) * K + (c1 & 3) * 16;
    int8_t* lA0 = As + wv * 1024;         // wave-uniform LDS bases
    int8_t* lA1 = As + 4096 + wv * 1024;
    int8_t* lB0 = Bs + wv * 1024;
    int8_t* lB1 = Bs + 4096 + wv * 1024;

    for (int k0 = 0; k0 < K; k0 += TBK) {
        async_load16(Xq + gA0 + k0, lA0);
        async_load16(Xq + gA1 + k0, lA1);
        async_load16(Wq + gB0 + k0, lB0);
        async_load16(Wq + gB1 + k0, lB1);
        __syncthreads();  // drains vmcnt(0) -> LDS valid

        int4v a[4], b[4];
#pragma unroll
        for (int i = 0; i < 4; ++i)
            a[i] = *(const int4v*)(As + (wn + i * 16 + r) * TBK + qd * 16);
#pragma unroll
        for (int j = 0; j < 4; ++j)
            b[j] = *(const int4v*)(Bs + (wm + j * 16 + r) * TBK + qd * 16);

#pragma unroll
        for (int i = 0; i < 4; ++i)
#pragma unroll
            for (int j = 0; j < 4; ++j)
                acc[i][j] = __builtin_amdgcn_mfma_i32_16x16x64_i8(
                    a[i], b[j], acc[i][j], 0, 0, 0);
        __syncthreads();  // protect LDS before next stage
    }

    // Epilogue: C/D layout col = lane&15 (m), row = qd*4 + reg (n).
#pragma unroll
    for (int j = 0; j < 4; ++j) {
        const int m = m0 + wm + j * 16 + r;
        const float rsm = rs[m];
        const float bm  = bias[m];
        const int   wsm = wsum[m];
#pragma unroll
        for (int i = 0; i < 4; ++i) {
            const int nb = n0 + wn + i * 16 + qd * 4;
#pragma unroll
            for (int v = 0; v < 4; ++v) {
                const int n = nb + v;
                const int ival = acc[i][j][v] - zp[n] * wsm;
                out[(size_t)n * M + m] = cs[n] * rsm * (float)ival + bm;
            }
        }
    }
}

// ---------------------------------------------------------------------------
extern "C" void kernel_launch(void* const* d_in, const int* in_sizes, int n_in,
                              void* d_out, int out_size, void* d_ws, size_t ws_size,
                              hipStream_t stream) {
    const float* x = (const float*)d_in[0];
    const float* W = (const float*)d_in[1];
    const float* b = (const float*)d_in[2];
    float* out = (float*)d_out;

    const int M = in_sizes[2];            // 4096
    const int K = in_sizes[1] / M;        // 4096
    const int N = in_sizes[0] / K;        // 8192

    // workspace carve-up (~50.4 MB total)
    int8_t* Xq = (int8_t*)d_ws;                       // N*K
    int8_t* Wq = Xq + (size_t)N * K;                  // M*K
    float* cs  = (float*)(Wq + (size_t)M * K);        // N
    int* zps   = (int*)(cs + N);                      // N
    float* rs  = (float*)(zps + N);                   // M
    int* wsum  = (int*)(rs + M);                      // M

    wquant_kernel<<<dim3(M), dim3(256), 0, stream>>>(W, Wq, rs, wsum, K);
    xquant_kernel<<<dim3(N), dim3(256), 0, stream>>>(x, Xq, cs, zps, K);
    gemm_i8_kernel<<<dim3(M / 128, N / 128), dim3(256), 0, stream>>>(
        Xq, Wq, cs, zps, rs, wsum, b, out, N, M, K);
}

// Round 4
// 443.260 us; speedup vs baseline: 1.0790x; 1.0790x over previous
//
#include <hip/hip_runtime.h>
#include <stdint.h>

// ---------------------------------------------------------------------------
// QuantLinear:  Y[n,m] = cs[n]*rs[m]*( Sint[n,m] - zp[n]*Wsum[m] ) + b[m]
// Sint = int32 GEMM of int8 Xq (asym per-token) x int8 Wq (sym per-row).
// R2: mfma_i32_32x32x32_i8, XOR-swizzled LDS (conflict-free b128 reads),
//     merged quant kernel, inv-scale multiply instead of per-elem IEEE div.
// (Resubmitted unchanged after two broker-level container failures.)
// ---------------------------------------------------------------------------

typedef __attribute__((ext_vector_type(4)))  int int4v;
typedef __attribute__((ext_vector_type(16))) int int16v;

__device__ __forceinline__ void async_load16(const void* g, void* l) {
    // global -> LDS DMA, 16B/lane; LDS dest = wave-uniform base + lane*16.
    __builtin_amdgcn_global_load_lds(
        (const __attribute__((address_space(1))) void*)g,
        (__attribute__((address_space(3))) void*)l, 16, 0, 0);
}

__device__ __forceinline__ int quant_clip(float v) {
    // matches np: clip(rint(v), -128, 127); rintf = round-half-even
    return (int)fminf(fmaxf(rintf(v), -128.f), 127.f);
}

// ---------------------------------------------------------------------------
// Merged quant kernel. Blocks [0,M) quantize W rows; blocks [M,M+N) quantize
// X token-rows. K floats per row, 256 threads/block, 4 x float4 per thread.
// ---------------------------------------------------------------------------
__global__ __launch_bounds__(256) void quant_kernel(
    const float* __restrict__ W, const float* __restrict__ X,
    int8_t* __restrict__ Wq, int8_t* __restrict__ Xq,
    float* __restrict__ row_scale, int* __restrict__ wsum,
    float* __restrict__ col_scale, int* __restrict__ zp, int M, int K) {
    const int blk  = blockIdx.x;
    const int tid  = threadIdx.x;
    const int lane = tid & 63;
    const int wv   = tid >> 6;
    __shared__ float sred0[4], sred1[4];
    __shared__ int   isum[4];

    if (blk < M) {
        // ---- weight path: symmetric per-row ----
        const int row = blk;
        const float4* w4 = (const float4*)(W + (size_t)row * K);
        float4 vals[4];
        float amax = 0.f;
#pragma unroll
        for (int i = 0; i < 4; ++i) {
            float4 v = w4[tid + i * 256];
            vals[i] = v;
            amax = fmaxf(amax, fmaxf(fmaxf(fabsf(v.x), fabsf(v.y)),
                                     fmaxf(fabsf(v.z), fabsf(v.w))));
        }
#pragma unroll
        for (int off = 32; off > 0; off >>= 1)
            amax = fmaxf(amax, __shfl_down(amax, off, 64));
        if (lane == 0) sred0[wv] = amax;
        __syncthreads();
        amax = fmaxf(fmaxf(sred0[0], sred0[1]), fmaxf(sred0[2], sred0[3]));

        const float scale = (amax > 0.f) ? (amax / 127.f) : 1.f;
        const float inv   = 1.f / scale;

        int ssum = 0;
        int* wq32 = (int*)(Wq + (size_t)row * K);
#pragma unroll
        for (int i = 0; i < 4; ++i) {
            float4 v = vals[i];
            int q0 = quant_clip(v.x * inv);
            int q1 = quant_clip(v.y * inv);
            int q2 = quant_clip(v.z * inv);
            int q3 = quant_clip(v.w * inv);
            ssum += q0 + q1 + q2 + q3;
            wq32[tid + i * 256] =
                (q0 & 0xff) | ((q1 & 0xff) << 8) | ((q2 & 0xff) << 16) | ((q3 & 0xff) << 24);
        }
#pragma unroll
        for (int off = 32; off > 0; off >>= 1)
            ssum += __shfl_down(ssum, off, 64);
        if (lane == 0) isum[wv] = ssum;
        __syncthreads();
        if (tid == 0) {
            wsum[row] = isum[0] + isum[1] + isum[2] + isum[3];
            row_scale[row] = scale;
        }
    } else {
        // ---- activation path: asymmetric per-token ----
        const int row = blk - M;
        const float4* x4 = (const float4*)(X + (size_t)row * K);
        float4 vals[4];
        float vmin = 3.402823466e+38f, vmax = -3.402823466e+38f;
#pragma unroll
        for (int i = 0; i < 4; ++i) {
            float4 v = x4[tid + i * 256];
            vals[i] = v;
            vmin = fminf(vmin, fminf(fminf(v.x, v.y), fminf(v.z, v.w)));
            vmax = fmaxf(vmax, fmaxf(fmaxf(v.x, v.y), fmaxf(v.z, v.w)));
        }
#pragma unroll
        for (int off = 32; off > 0; off >>= 1) {
            vmin = fminf(vmin, __shfl_down(vmin, off, 64));
            vmax = fmaxf(vmax, __shfl_down(vmax, off, 64));
        }
        if (lane == 0) { sred0[wv] = vmin; sred1[wv] = vmax; }
        __syncthreads();
        vmin = fminf(fminf(sred0[0], sred0[1]), fminf(sred0[2], sred0[3]));
        vmax = fmaxf(fmaxf(sred1[0], sred1[1]), fmaxf(sred1[2], sred1[3]));

        const float rng   = vmax - vmin;
        const float scale = (rng > 0.f) ? (rng / 255.f) : 1.f;
        const float inv   = 1.f / scale;
        const float zpf   = fminf(fmaxf(rintf(-128.f - vmin * inv), -128.f), 127.f);

        int* xq32 = (int*)(Xq + (size_t)row * K);
#pragma unroll
        for (int i = 0; i < 4; ++i) {
            float4 v = vals[i];
            int q0 = quant_clip(v.x * inv + zpf);
            int q1 = quant_clip(v.y * inv + zpf);
            int q2 = quant_clip(v.z * inv + zpf);
            int q3 = quant_clip(v.w * inv + zpf);
            xq32[tid + i * 256] =
                (q0 & 0xff) | ((q1 & 0xff) << 8) | ((q2 & 0xff) << 16) | ((q3 & 0xff) << 24);
        }
        if (tid == 0) {
            col_scale[row] = scale;
            zp[row] = (int)zpf;
        }
    }
}

// ---------------------------------------------------------------------------
// int8 GEMM. Block tile 128(N) x 128(M), BK=64 bytes. 4 waves in 2x2; each
// wave owns 64x64 via 2x2 frags of mfma_i32_32x32x32_i8 (2 k-steps/iter).
//
// LDS layout: [128 rows][4 chunks of 16B], chunk (r,c) stored at physical
// col c ^ ((r>>1)&3). The XOR is applied on the *global* source address at
// staging time (global_load_lds dest is fixed at base+lane*16), and again at
// read time -> 8 consecutive reader lanes cover all 8 bank-groups.
// ---------------------------------------------------------------------------
__global__ __launch_bounds__(256) void gemm_i8_kernel(
    const int8_t* __restrict__ Xq, const int8_t* __restrict__ Wq,
    const float* __restrict__ cs, const int* __restrict__ zp,
    const float* __restrict__ rs, const int* __restrict__ wsum,
    const float* __restrict__ bias, float* __restrict__ out,
    int N, int M, int K) {
    __shared__ __align__(16) int8_t As[128 * 64];  // 8 KB
    __shared__ __align__(16) int8_t Bs[128 * 64];  // 8 KB

    const int t    = threadIdx.x;
    const int wv   = t >> 6;
    const int lane = t & 63;
    const int r32  = lane & 31;   // MFMA row within 32-frag
    const int half = lane >> 5;   // k-half selector

    const int m0 = blockIdx.x * 128;
    const int n0 = blockIdx.y * 128;
    const int wn = (wv >> 1) * 64;
    const int wm = (wv & 1) * 64;

    int16v acc[2][2];
#pragma unroll
    for (int i = 0; i < 2; ++i)
#pragma unroll
        for (int j = 0; j < 2; ++j)
            acc[i][j] = (int16v)(0);

    // -- staging addresses (chunk ci = it*256 + t; r = ci>>2, pc = ci&3) --
    const int r0 = t >> 2;
    const int c0 = (t & 3) ^ ((r0 >> 1) & 3);   // swizzled source col
    // second chunk: r1 = 64 + r0, and ((r1>>1)&3) == ((r0>>1)&3) -> same c0
    const size_t gA0 = (size_t)(n0 + r0) * K + c0 * 16;
    const size_t gA1 = (size_t)(n0 + 64 + r0) * K + c0 * 16;
    const size_t gB0 = (size_t)(m0 + r0) * K + c0 * 16;
    const size_t gB1 = (size_t)(m0 + 64 + r0) * K + c0 * 16;
    int8_t* lA0 = As + wv * 1024;          // wave-uniform LDS bases
    int8_t* lA1 = As + 4096 + wv * 1024;
    int8_t* lB0 = Bs + wv * 1024;
    int8_t* lB1 = Bs + 4096 + wv * 1024;

    // -- reader bases: A rows wn+in*32+r32, B rows wm+jm*32+r32 --
    int abase[2], bbase[2], asw[2], bsw[2];
#pragma unroll
    for (int i = 0; i < 2; ++i) {
        const int ra = wn + i * 32 + r32;
        abase[i] = ra * 64;
        asw[i]   = (ra >> 1) & 3;
        const int rb = wm + i * 32 + r32;
        bbase[i] = rb * 64;
        bsw[i]   = (rb >> 1) & 3;
    }

    for (int k0 = 0; k0 < K; k0 += 64) {
        async_load16(Xq + gA0 + k0, lA0);
        async_load16(Xq + gA1 + k0, lA1);
        async_load16(Wq + gB0 + k0, lB0);
        async_load16(Wq + gB1 + k0, lB1);
        __syncthreads();  // drains vmcnt -> LDS valid

        int4v a[2][2], b[2][2];  // [kstep][frag]
#pragma unroll
        for (int s = 0; s < 2; ++s) {
            const int ch = s * 2 + half;
#pragma unroll
            for (int i = 0; i < 2; ++i) {
                a[s][i] = *(const int4v*)(As + abase[i] + ((ch ^ asw[i]) << 4));
                b[s][i] = *(const int4v*)(Bs + bbase[i] + ((ch ^ bsw[i]) << 4));
            }
        }
#pragma unroll
        for (int s = 0; s < 2; ++s)
#pragma unroll
            for (int i = 0; i < 2; ++i)
#pragma unroll
                for (int j = 0; j < 2; ++j)
                    acc[i][j] = __builtin_amdgcn_mfma_i32_32x32x32_i8(
                        a[s][i], b[s][j], acc[i][j], 0, 0, 0);
        __syncthreads();  // protect LDS before next stage
    }

    // Epilogue. 32x32 C/D: col(m) = lane&31, row(n) = (reg&3)+8*(reg>>2)+4*half
    int   mm[2];
    float rsv[2], bv[2];
    int   wsv[2];
#pragma unroll
    for (int j = 0; j < 2; ++j) {
        mm[j]  = m0 + wm + j * 32 + r32;
        rsv[j] = rs[mm[j]];
        bv[j]  = bias[mm[j]];
        wsv[j] = wsum[mm[j]];
    }
#pragma unroll
    for (int i = 0; i < 2; ++i) {
        const int nb = n0 + wn + i * 32 + half * 4;
#pragma unroll
        for (int reg = 0; reg < 16; ++reg) {
            const int n = nb + (reg & 3) + 8 * (reg >> 2);
            const float csn = cs[n];
            const int   zpn = zp[n];
#pragma unroll
            for (int j = 0; j < 2; ++j) {
                const int ival = acc[i][j][reg] - zpn * wsv[j];
                out[(size_t)n * M + mm[j]] = csn * rsv[j] * (float)ival + bv[j];
            }
        }
    }
}

// ---------------------------------------------------------------------------
extern "C" void kernel_launch(void* const* d_in, const int* in_sizes, int n_in,
                              void* d_out, int out_size, void* d_ws, size_t ws_size,
                              hipStream_t stream) {
    const float* x = (const float*)d_in[0];
    const float* W = (const float*)d_in[1];
    const float* b = (const float*)d_in[2];
    float* out = (float*)d_out;

    const int M = in_sizes[2];            // 4096
    const int K = in_sizes[1] / M;        // 4096
    const int N = in_sizes[0] / K;        // 8192

    // workspace carve-up (~50.4 MB)
    int8_t* Xq = (int8_t*)d_ws;                       // N*K
    int8_t* Wq = Xq + (size_t)N * K;                  // M*K
    float* cs  = (float*)(Wq + (size_t)M * K);        // N
    int* zps   = (int*)(cs + N);                      // N
    float* rs  = (float*)(zps + N);                   // M
    int* wsum  = (int*)(rs + M);                      // M

    quant_kernel<<<dim3(M + N), dim3(256), 0, stream>>>(
        W, x, Wq, Xq, rs, wsum, cs, zps, M, K);
    gemm_i8_kernel<<<dim3(M / 128, N / 128), dim3(256), 0, stream>>>(
        Xq, Wq, cs, zps, rs, wsum, b, out, N, M, K);
}